// Round 22
// baseline (176.171 us; speedup 1.0000x reference)
//
#include <hip/hip_runtime.h>
#include <math.h>

#define HD 64

typedef _Float16 half8 __attribute__((ext_vector_type(8)));
typedef _Float16 half4v __attribute__((ext_vector_type(4)));
typedef float floatx4 __attribute__((ext_vector_type(4)));

__device__ __forceinline__ float silu_f(float x) {
    return x * __builtin_amdgcn_rcpf(1.0f + __expf(-x));
}

// ------- pre_wconv_count: node_pre blocks | wconv blocks | count blocks ------
__global__ __launch_bounds__(256) void pre_wconv_count(
    const float* __restrict__ X,
    const float* __restrict__ Wt0, const float* __restrict__ Wt1, const float* __restrict__ Wt2,
    float* __restrict__ Tn, _Float16* __restrict__ TnH, int N, int nbPre,
    const float* __restrict__ Ws1, const float* __restrict__ Ws2, const float* __restrict__ Ws3,
    _Float16* __restrict__ W1f, _Float16* __restrict__ W2f, _Float16* __restrict__ W3f,
    const int* __restrict__ edge_index, int* __restrict__ cnt, int E)
{
    if (blockIdx.x >= nbPre + 144) {
        int e = (blockIdx.x - nbPre - 144) * 256 + threadIdx.x;
        if (e < E) atomicAdd(&cnt[edge_index[e]], 1);
        return;
    }
    if (blockIdx.x >= nbPre) {
        int id = (blockIdx.x - nbPre) * 256 + threadIdx.x;
        if (id < 4096) {
            int i = id & 7, l = (id >> 3) & 63, t = id >> 9;    // t in 0..7
            int s = t >> 2, nt = t & 3;
            int k = s * 32 + (l >> 4) * 8 + i;
            int n = nt * 16 + (l & 15);
            W1f[id] = (k < 48) ? (_Float16)Ws1[k * 64 + n] : (_Float16)0.f;
        } else if (id < 4096 + 8192) {
            int j = id - 4096;
            int i = j & 7, l = (j >> 3) & 63, t = j >> 9;       // t in 0..15
            int s = t >> 3, nt = t & 7;
            int k = s * 32 + (l >> 4) * 8 + i;
            int n = nt * 16 + (l & 15);
            W2f[j] = (_Float16)Ws2[k * 128 + n];
        } else if (id < 4096 + 8192 + 24576) {
            int j = id - 4096 - 8192;
            int i = j & 7, l = (j >> 3) & 63, t = j >> 9;       // t in 0..47
            int s = t / 12, nt = t % 12;
            int k = s * 32 + (l >> 4) * 8 + i;
            int n = nt * 16 + (l & 15);
            W3f[j] = (_Float16)Ws3[k * 192 + n];
        }
        return;
    }

    int sub = threadIdx.x >> 6;
    int h = threadIdx.x & 63;
    int n = blockIdx.x * 4 + sub;
    int nn = (n < N) ? n : (N - 1);

    const float* Xb = X + (size_t)nn * 9 * HD + h;
    float x[9];
    float nrm = 0.f;
#pragma unroll
    for (int i = 0; i < 9; ++i) { x[i] = Xb[i * HD]; nrm += x[i] * x[i]; }
    float inv = 1.0f / (nrm + 1.0f);
#pragma unroll
    for (int i = 0; i < 9; ++i) x[i] *= inv;

    float I0 = (x[0] + x[4] + x[8]) * (1.0f / 3.0f);
    __shared__ float comp[4][10][HD];
    comp[sub][0][h] = I0;
    comp[sub][1][h] = 0.5f * (x[1] - x[3]);
    comp[sub][2][h] = 0.5f * (x[2] - x[6]);
    comp[sub][3][h] = 0.5f * (x[5] - x[7]);
    comp[sub][4][h] = x[0] - I0;
    comp[sub][5][h] = 0.5f * (x[1] + x[3]);
    comp[sub][6][h] = 0.5f * (x[2] + x[6]);
    comp[sub][7][h] = x[4] - I0;
    comp[sub][8][h] = 0.5f * (x[5] + x[7]);
    comp[sub][9][h] = x[8] - I0;
    __syncthreads();
    float acc[10];
#pragma unroll
    for (int i = 0; i < 10; ++i) acc[i] = 0.f;
    for (int k = 0; k < HD; ++k) {
        float w0 = Wt0[k * HD + h];
        float w1 = Wt1[k * HD + h];
        float w2 = Wt2[k * HD + h];
        acc[0] += comp[sub][0][k] * w0;
        acc[1] += comp[sub][1][k] * w1;
        acc[2] += comp[sub][2][k] * w1;
        acc[3] += comp[sub][3][k] * w1;
#pragma unroll
        for (int j = 0; j < 6; ++j) acc[4 + j] += comp[sub][4 + j][k] * w2;
    }
    if (n < N) {
        float* tp = Tn + (size_t)n * 640 + h;
        _Float16* th = TnH + (size_t)n * 640 + h;
#pragma unroll
        for (int i = 0; i < 10; ++i) {
            tp[i * 64] = acc[i];
            th[i * 64] = (_Float16)acc[i];
        }
    }
}

// ---------------- single-block scan (N<=64K): offs + curs + offs[N] ----------
__global__ __launch_bounds__(1024) void scan_kernel(
    const int* __restrict__ cnt, int* __restrict__ offs, int* __restrict__ curs, int N)
{
    __shared__ int partials[16];
    __shared__ int base_s;
    int tid = threadIdx.x, wid = tid >> 6, lane = tid & 63;
    if (tid == 0) base_s = 0;
    __syncthreads();
    for (int start = 0; start < N; start += 1024) {
        int i = start + tid;
        int v = (i < N) ? cnt[i] : 0;
        int s = v;
#pragma unroll
        for (int d = 1; d < 64; d <<= 1) {
            int t = __shfl_up(s, d, 64);
            if (lane >= d) s += t;
        }
        if (lane == 63) partials[wid] = s;
        __syncthreads();
        if (tid == 0) {
            int run = base_s;
#pragma unroll
            for (int w = 0; w < 16; ++w) { int t = partials[w]; partials[w] = run; run += t; }
            base_s = run;
        }
        __syncthreads();
        int excl = partials[wid] + s - v;
        if (i < N) { offs[i] = excl; curs[i] = excl; }
        __syncthreads();
    }
    if (tid == 0) offs[N] = base_s;
}

// ---------------- fused MLP via MFMA fp16 — 128 edges/block, column-split ----
// 4 waves share TWO 64-edge sets (rows 0..63 = set A, 64..127 = set B) in one
// LDS tile. Each weight fragment feeds 8 MFMAs (L2 weight traffic halved vs
// r21). L3 weights (12 frags, 48 VGPR) held across both sets. Inline place.
__global__ __launch_bounds__(256, 4) void mlp_mfma(
    const float* __restrict__ edge_attr, const float* __restrict__ charges,
    const float* __restrict__ edge_weight, const int* __restrict__ edge_index,
    int* __restrict__ curs, int* __restrict__ colP,
    const _Float16* __restrict__ W1f, const float* __restrict__ bs1,
    const _Float16* __restrict__ W2f, const float* __restrict__ bs2,
    const _Float16* __restrict__ W3f, const float* __restrict__ bs3,
    _Float16* __restrict__ bufH, int E)
{
    __shared__ __align__(16) _Float16 act[128][200];
    __shared__ float cvsS[128];
    __shared__ int rankSS[128];

    int tid = threadIdx.x;
    int wv = tid >> 6, l = tid & 63;
    int base = blockIdx.x * 128;
    int row16 = l & 15, quad = l >> 4;

    // ---- block staging: 128 edges x 16 float4-slots, 8 per thread ----
#pragma unroll
    for (int i = 0; i < 8; ++i) {
        int slot = tid + i * 256;
        int e_l = slot >> 4, f = slot & 15;
        int e = base + e_l;
        int ee = (e < E) ? e : (E - 1);
        float4 v = make_float4(0.f, 0.f, 0.f, 0.f);
        if (f < 8) {
            v = *(const float4*)(edge_attr + (size_t)ee * 32 + f * 4);
        } else if (f < 10) {
            int r = edge_index[ee];
            v = *(const float4*)(charges + (size_t)r * 8 + (f - 8) * 4);
        } else if (f < 12) {
            int c = edge_index[E + ee];
            v = *(const float4*)(charges + (size_t)c * 8 + (f - 10) * 4);
        }
        half4v hv = { (_Float16)v.x, (_Float16)v.y, (_Float16)v.z, (_Float16)v.w };
        *(half4v*)&act[e_l][f * 4] = hv;
    }
    if (tid < 128) {
        int e = base + tid;
        bool valid = (e < E);
        int ee = valid ? e : (E - 1);
        int row = edge_index[ee];
        int col = edge_index[E + ee];
        int rk = 0;
        if (valid) {
            rk = atomicAdd(&curs[row], 1);
            colP[rk] = col;
        }
        rankSS[tid] = rk;
        float wgt = edge_weight[ee];
        float cv = 0.5f * (__cosf(wgt * 0.6283185307179586f) + 1.0f);
        cvsS[tid] = (wgt < 5.0f) ? cv : 0.0f;
    }
    __syncthreads();

    // ---- layer 1: wave computes nt=wv for all 8 m-tiles -> h1 [128,192) ----
    {
        half8 w0 = *(const half8*)(W1f + ((size_t)(0 * 4 + wv) * 64 + l) * 8);
        half8 w1 = *(const half8*)(W1f + ((size_t)(1 * 4 + wv) * 64 + l) * 8);
        floatx4 acc1[8];
#pragma unroll
        for (int m = 0; m < 8; ++m) {
            floatx4 c = {0.f, 0.f, 0.f, 0.f};
            c = __builtin_amdgcn_mfma_f32_16x16x32_f16(
                    *(const half8*)&act[m * 16 + row16][quad * 8], w0, c, 0, 0, 0);
            c = __builtin_amdgcn_mfma_f32_16x16x32_f16(
                    *(const half8*)&act[m * 16 + row16][32 + quad * 8], w1, c, 0, 0, 0);
            acc1[m] = c;
        }
        float b = bs1[wv * 16 + row16];
#pragma unroll
        for (int m = 0; m < 8; ++m)
#pragma unroll
            for (int r = 0; r < 4; ++r)
                act[m * 16 + quad * 4 + r][128 + wv * 16 + row16] =
                    (_Float16)silu_f(acc1[m][r] + b);
    }
    __syncthreads();

    // ---- layer 2: wave computes nt=wv*2+j (j=0,1) -> h2 [0,128) ----
    {
        floatx4 acc2[8][2];
#pragma unroll
        for (int m = 0; m < 8; ++m)
#pragma unroll
            for (int j = 0; j < 2; ++j) acc2[m][j] = (floatx4){0.f, 0.f, 0.f, 0.f};
#pragma unroll
        for (int s = 0; s < 2; ++s) {
            half8 w0 = *(const half8*)(W2f + ((size_t)(s * 8 + wv * 2 + 0) * 64 + l) * 8);
            half8 w1 = *(const half8*)(W2f + ((size_t)(s * 8 + wv * 2 + 1) * 64 + l) * 8);
#pragma unroll
            for (int m = 0; m < 8; ++m) {
                half8 a = *(const half8*)&act[m * 16 + row16][128 + s * 32 + quad * 8];
                acc2[m][0] = __builtin_amdgcn_mfma_f32_16x16x32_f16(a, w0, acc2[m][0], 0, 0, 0);
                acc2[m][1] = __builtin_amdgcn_mfma_f32_16x16x32_f16(a, w1, acc2[m][1], 0, 0, 0);
            }
        }
        float b0 = bs2[(wv * 2 + 0) * 16 + row16];
        float b1 = bs2[(wv * 2 + 1) * 16 + row16];
#pragma unroll
        for (int m = 0; m < 8; ++m)
#pragma unroll
            for (int r = 0; r < 4; ++r) {
                act[m * 16 + quad * 4 + r][(wv * 2 + 0) * 16 + row16] =
                    (_Float16)silu_f(acc2[m][0][r] + b0);
                act[m * 16 + quad * 4 + r][(wv * 2 + 1) * 16 + row16] =
                    (_Float16)silu_f(acc2[m][1][r] + b1);
            }
    }
    __syncthreads();

    // ---- layer 3: w3 (12 frags) held across set A and set B ----
    half8 w3[12];
#pragma unroll
    for (int s = 0; s < 4; ++s)
#pragma unroll
        for (int j = 0; j < 3; ++j)
            w3[s * 3 + j] = *(const half8*)(W3f + ((size_t)(s * 12 + wv * 3 + j) * 64 + l) * 8);

    float b0 = bs3[(wv * 3 + 0) * 16 + row16];
    float b1 = bs3[(wv * 3 + 1) * 16 + row16];
    float b2 = bs3[(wv * 3 + 2) * 16 + row16];

    // --- set A compute (rows 0..63) ---
    floatx4 accA[4][3];
#pragma unroll
    for (int m = 0; m < 4; ++m)
#pragma unroll
        for (int j = 0; j < 3; ++j) accA[m][j] = (floatx4){0.f, 0.f, 0.f, 0.f};
#pragma unroll
    for (int s = 0; s < 4; ++s)
#pragma unroll
        for (int m = 0; m < 4; ++m) {
            half8 a = *(const half8*)&act[m * 16 + row16][s * 32 + quad * 8];
            accA[m][0] = __builtin_amdgcn_mfma_f32_16x16x32_f16(a, w3[s * 3 + 0], accA[m][0], 0, 0, 0);
            accA[m][1] = __builtin_amdgcn_mfma_f32_16x16x32_f16(a, w3[s * 3 + 1], accA[m][1], 0, 0, 0);
            accA[m][2] = __builtin_amdgcn_mfma_f32_16x16x32_f16(a, w3[s * 3 + 2], accA[m][2], 0, 0, 0);
        }
    __syncthreads();   // all h2-A reads done block-wide

    // --- set A park (rows 0..63) + set B compute (rows 64..127): disjoint ---
#pragma unroll
    for (int m = 0; m < 4; ++m) {
#pragma unroll
        for (int r = 0; r < 4; ++r) {
            float cv = cvsS[m * 16 + quad * 4 + r];
            act[m * 16 + quad * 4 + r][(wv * 3 + 0) * 16 + row16] =
                (_Float16)(silu_f(accA[m][0][r] + b0) * cv);
            act[m * 16 + quad * 4 + r][(wv * 3 + 1) * 16 + row16] =
                (_Float16)(silu_f(accA[m][1][r] + b1) * cv);
            act[m * 16 + quad * 4 + r][(wv * 3 + 2) * 16 + row16] =
                (_Float16)(silu_f(accA[m][2][r] + b2) * cv);
        }
    }
    floatx4 accB[4][3];
#pragma unroll
    for (int m = 0; m < 4; ++m)
#pragma unroll
        for (int j = 0; j < 3; ++j) accB[m][j] = (floatx4){0.f, 0.f, 0.f, 0.f};
#pragma unroll
    for (int s = 0; s < 4; ++s)
#pragma unroll
        for (int m = 0; m < 4; ++m) {
            half8 a = *(const half8*)&act[64 + m * 16 + row16][s * 32 + quad * 8];
            accB[m][0] = __builtin_amdgcn_mfma_f32_16x16x32_f16(a, w3[s * 3 + 0], accB[m][0], 0, 0, 0);
            accB[m][1] = __builtin_amdgcn_mfma_f32_16x16x32_f16(a, w3[s * 3 + 1], accB[m][1], 0, 0, 0);
            accB[m][2] = __builtin_amdgcn_mfma_f32_16x16x32_f16(a, w3[s * 3 + 2], accB[m][2], 0, 0, 0);
        }
    __syncthreads();   // set-A parks visible; all h2-B reads done

    // --- flush set A + park set B (disjoint row ranges) ---
    {
        int fr = tid >> 2;
        int ef = base + fr;
        if (ef < E) {
            _Float16* dst = bufH + (size_t)rankSS[fr] * 192;
#pragma unroll
            for (int i = 0; i < 6; ++i) {
                int j = (tid & 3) + i * 4;
                *(half8*)(dst + j * 8) = *(const half8*)&act[fr][j * 8];
            }
        }
    }
#pragma unroll
    for (int m = 0; m < 4; ++m) {
#pragma unroll
        for (int r = 0; r < 4; ++r) {
            float cv = cvsS[64 + m * 16 + quad * 4 + r];
            act[64 + m * 16 + quad * 4 + r][(wv * 3 + 0) * 16 + row16] =
                (_Float16)(silu_f(accB[m][0][r] + b0) * cv);
            act[64 + m * 16 + quad * 4 + r][(wv * 3 + 1) * 16 + row16] =
                (_Float16)(silu_f(accB[m][1][r] + b1) * cv);
            act[64 + m * 16 + quad * 4 + r][(wv * 3 + 2) * 16 + row16] =
                (_Float16)(silu_f(accB[m][2][r] + b2) * cv);
        }
    }
    __syncthreads();   // set-B parks visible

    // --- flush set B ---
    {
        int fr = 64 + (tid >> 2);
        int ef = base + fr;
        if (ef < E) {
            _Float16* dst = bufH + (size_t)rankSS[fr] * 192;
#pragma unroll
            for (int i = 0; i < 6; ++i) {
                int j = (tid & 3) + i * 4;
                *(half8*)(dst + j * 8) = *(const half8*)&act[fr][j * 8];
            }
        }
    }
}

// ---------------- msg kernel: 1 node/block, 4-way edge split, fp16 Mn --------
__global__ __launch_bounds__(256) void msg_kernel(
    const _Float16* __restrict__ bufH, const int* __restrict__ colP,
    const int* __restrict__ offs, const _Float16* __restrict__ TnH,
    _Float16* __restrict__ MnH, int N)
{
    __shared__ float part[4][10][64];
    int qtr = threadIdx.x >> 6;
    int lane = threadIdx.x & 63;
    int n = blockIdx.x;
    int beg = offs[n], end = offs[n + 1];
    int len = end - beg;
    int s0 = beg + (len * qtr) / 4;
    int s1 = beg + (len * (qtr + 1)) / 4;

    float a0 = 0.f, a1 = 0.f, a2 = 0.f, a3 = 0.f, a4 = 0.f;
    float a5 = 0.f, a6 = 0.f, a7 = 0.f, a8 = 0.f, a9 = 0.f;
#pragma unroll 2
    for (int idx = s0; idx < s1; ++idx) {
        int c = colP[idx];
        const _Float16* wp = bufH + (size_t)idx * 192;
        float w0 = (float)wp[lane];
        float w1 = (float)wp[64 + lane];
        float w2 = (float)wp[128 + lane];
        const _Float16* tp = TnH + (size_t)c * 640;
        a0 += w0 * (float)tp[lane];
        a1 += w1 * (float)tp[64 + lane];
        a2 += w1 * (float)tp[128 + lane];
        a3 += w1 * (float)tp[192 + lane];
        a4 += w2 * (float)tp[256 + lane];
        a5 += w2 * (float)tp[320 + lane];
        a6 += w2 * (float)tp[384 + lane];
        a7 += w2 * (float)tp[448 + lane];
        a8 += w2 * (float)tp[512 + lane];
        a9 += w2 * (float)tp[576 + lane];
    }
    part[qtr][0][lane] = a0; part[qtr][1][lane] = a1;
    part[qtr][2][lane] = a2; part[qtr][3][lane] = a3;
    part[qtr][4][lane] = a4; part[qtr][5][lane] = a5;
    part[qtr][6][lane] = a6; part[qtr][7][lane] = a7;
    part[qtr][8][lane] = a8; part[qtr][9][lane] = a9;
    __syncthreads();

    if (qtr < 2) {
        _Float16* mp = MnH + (size_t)n * 640;
#pragma unroll
        for (int j = 0; j < 5; ++j) {
            int c = qtr * 5 + j;
            mp[c * 64 + lane] = (_Float16)((part[0][c][lane] + part[1][c][lane])
                                         + (part[2][c][lane] + part[3][c][lane]));
        }
    }
}

// ---------------- node_post: 4 nodes/block (256 thr) -------------------------
__global__ __launch_bounds__(256) void node_post(
    const float* __restrict__ X,
    const float* __restrict__ Tn, const _Float16* __restrict__ MnH,
    const float* __restrict__ Wt3, const float* __restrict__ Wt4, const float* __restrict__ Wt5,
    float* __restrict__ out, int N)
{
    int sub = threadIdx.x >> 6;
    int h = threadIdx.x & 63;
    int n = blockIdx.x * 4 + sub;
    int nn = (n < N) ? n : (N - 1);

    const float* Xb = X + (size_t)nn * 9 * HD + h;
    float x[9];
    float nr = 0.f;
#pragma unroll
    for (int i = 0; i < 9; ++i) { x[i] = Xb[i * HD]; nr += x[i] * x[i]; }
    float xinv = 1.0f / (nr + 1.0f);
#pragma unroll
    for (int i = 0; i < 9; ++i) x[i] *= xinv;

    const float* tp = Tn + (size_t)nn * 640 + h;
    const _Float16* mp = MnH + (size_t)nn * 640 + h;
    float yI = tp[0], mI = (float)mp[0];
    float yA[3], yS[6], mA[3], mS[6];
#pragma unroll
    for (int j = 0; j < 3; ++j) { yA[j] = tp[(1 + j) * 64]; mA[j] = (float)mp[(1 + j) * 64]; }
#pragma unroll
    for (int j = 0; j < 6; ++j) { yS[j] = tp[(4 + j) * 64]; mS[j] = (float)mp[(4 + j) * 64]; }

    float M[3][3] = {
        { mI + mS[0],     mA[0] + mS[1],   mA[1] + mS[2] },
        { -mA[0] + mS[1], mI + mS[3],      mA[2] + mS[4] },
        { -mA[1] + mS[2], -mA[2] + mS[4],  mI + mS[5] } };
    float Y[3][3] = {
        { yI + yS[0],     yA[0] + yS[1],   yA[1] + yS[2] },
        { -yA[0] + yS[1], yI + yS[3],      yA[2] + yS[4] },
        { -yA[1] + yS[2], -yA[2] + yS[4],  yI + yS[5] } };

    float Cm[3][3];
    float nrm = 0.f;
#pragma unroll
    for (int a = 0; a < 3; ++a) {
#pragma unroll
        for (int b = 0; b < 3; ++b) {
            float s = 0.f;
#pragma unroll
            for (int c = 0; c < 3; ++c) s += M[a][c] * Y[c][b] + Y[a][c] * M[c][b];
            Cm[a][b] = s;
            nrm += s * s;
        }
    }
    float inv = 1.0f / (nrm + 1.0f);
    float tr3 = (Cm[0][0] + Cm[1][1] + Cm[2][2]) * (1.0f / 3.0f);

    __shared__ float comp[4][10][HD];
    comp[sub][0][h] = tr3 * inv;
    comp[sub][1][h] = 0.5f * (Cm[0][1] - Cm[1][0]) * inv;
    comp[sub][2][h] = 0.5f * (Cm[0][2] - Cm[2][0]) * inv;
    comp[sub][3][h] = 0.5f * (Cm[1][2] - Cm[2][1]) * inv;
    comp[sub][4][h] = (Cm[0][0] - tr3) * inv;
    comp[sub][5][h] = 0.5f * (Cm[0][1] + Cm[1][0]) * inv;
    comp[sub][6][h] = 0.5f * (Cm[0][2] + Cm[2][0]) * inv;
    comp[sub][7][h] = (Cm[1][1] - tr3) * inv;
    comp[sub][8][h] = 0.5f * (Cm[1][2] + Cm[2][1]) * inv;
    comp[sub][9][h] = (Cm[2][2] - tr3) * inv;
    __syncthreads();

    float acc[10];
#pragma unroll
    for (int i = 0; i < 10; ++i) acc[i] = 0.f;
    for (int k = 0; k < HD; ++k) {
        float w3 = Wt3[k * HD + h];
        float w4 = Wt4[k * HD + h];
        float w5 = Wt5[k * HD + h];
        acc[0] += comp[sub][0][k] * w3;
        acc[1] += comp[sub][1][k] * w4;
        acc[2] += comp[sub][2][k] * w4;
        acc[3] += comp[sub][3][k] * w4;
#pragma unroll
        for (int j = 0; j < 6; ++j) acc[4 + j] += comp[sub][4 + j][k] * w5;
    }
    float D[3][3] = {
        { acc[0] + acc[4],  acc[1] + acc[5],  acc[2] + acc[6] },
        { -acc[1] + acc[5], acc[0] + acc[7],  acc[3] + acc[8] },
        { -acc[2] + acc[6], -acc[3] + acc[8], acc[0] + acc[9] } };

    if (n < N) {
        float* ob = out + (size_t)n * 9 * HD + h;
#pragma unroll
        for (int a = 0; a < 3; ++a) {
#pragma unroll
            for (int b = 0; b < 3; ++b) {
                float s = 0.f;
#pragma unroll
                for (int c = 0; c < 3; ++c) s += D[a][c] * D[c][b];
                ob[(a * 3 + b) * HD] = x[a * 3 + b] + D[a][b] + s;
            }
        }
    }
}

// ---------------- launch ------------------------------------------------------
extern "C" void kernel_launch(void* const* d_in, const int* in_sizes, int n_in,
                              void* d_out, int out_size, void* d_ws, size_t ws_size,
                              hipStream_t stream)
{
    const float* X           = (const float*)d_in[0];
    const float* charges     = (const float*)d_in[1];
    const float* edge_weight = (const float*)d_in[2];
    const float* edge_attr   = (const float*)d_in[3];
    const int*   edge_index  = (const int*)d_in[4];
    const float* Ws1 = (const float*)d_in[5];
    const float* bs1 = (const float*)d_in[6];
    const float* Ws2 = (const float*)d_in[7];
    const float* bs2 = (const float*)d_in[8];
    const float* Ws3 = (const float*)d_in[9];
    const float* bs3 = (const float*)d_in[10];
    const float* Wt0 = (const float*)d_in[11];
    const float* Wt1 = (const float*)d_in[12];
    const float* Wt2 = (const float*)d_in[13];
    const float* Wt3 = (const float*)d_in[14];
    const float* Wt4 = (const float*)d_in[15];
    const float* Wt5 = (const float*)d_in[16];

    int N = in_sizes[0] / (9 * HD);
    int E = in_sizes[2];

    float* ws = (float*)d_ws;
    float* Tn  = ws;                                   // N*640 f32
    _Float16* TnH  = (_Float16*)(Tn + (size_t)N * 640);   // N*640 f16
    _Float16* MnH  = TnH + (size_t)N * 640;               // N*640 f16
    _Float16* bufH = MnH + (size_t)N * 640;               // E*192 f16 (CSR slots)
    int* cnt   = (int*)(bufH + (size_t)E * 192);       // N
    int* offs  = cnt + N;                              // N+1
    int* curs  = offs + N + 1;                         // N
    int* colP  = curs + N;                             // E
    size_t fofs = ((size_t)((char*)(colP + E) - (char*)d_ws) + 15) & ~(size_t)15;
    _Float16* W1f = (_Float16*)((char*)d_ws + fofs);   // 4096
    _Float16* W2f = W1f + 4096;                        // 8192
    _Float16* W3f = W2f + 8192;                        // 24576

    hipMemsetAsync(cnt, 0, (size_t)N * sizeof(int), stream);

    int nbPre = (N + 3) / 4;
    int nbE256 = (E + 255) / 256;
    pre_wconv_count<<<nbPre + 144 + nbE256, 256, 0, stream>>>(
        X, Wt0, Wt1, Wt2, Tn, TnH, N, nbPre,
        Ws1, Ws2, Ws3, W1f, W2f, W3f, edge_index, cnt, E);

    scan_kernel<<<1, 1024, 0, stream>>>(cnt, offs, curs, N);

    int nbE128 = (E + 127) / 128;
    mlp_mfma<<<nbE128, 256, 0, stream>>>(edge_attr, charges, edge_weight, edge_index,
                                         curs, colP, W1f, bs1, W2f, bs2, W3f, bs3, bufH, E);

    msg_kernel<<<N, 256, 0, stream>>>(bufH, colP, offs, TnH, MnH, N);

    node_post<<<(N + 3) / 4, 256, 0, stream>>>(X, Tn, MnH, Wt3, Wt4, Wt5, (float*)d_out, N);
}

// Round 23
// 156.655 us; speedup vs baseline: 1.1246x; 1.1246x over previous
//
#include <hip/hip_runtime.h>
#include <math.h>

#define HD 64

typedef _Float16 half8 __attribute__((ext_vector_type(8)));
typedef _Float16 half4v __attribute__((ext_vector_type(4)));
typedef float floatx4 __attribute__((ext_vector_type(4)));

__device__ __forceinline__ float silu_f(float x) {
    return x * __builtin_amdgcn_rcpf(1.0f + __expf(-x));
}

// ------- pre_wconv_count: node_pre blocks | wconv blocks | count blocks ------
__global__ __launch_bounds__(256) void pre_wconv_count(
    const float* __restrict__ X,
    const float* __restrict__ Wt0, const float* __restrict__ Wt1, const float* __restrict__ Wt2,
    float* __restrict__ Tn, _Float16* __restrict__ TnH, int N, int nbPre,
    const float* __restrict__ Ws1, const float* __restrict__ Ws2, const float* __restrict__ Ws3,
    _Float16* __restrict__ W1f, _Float16* __restrict__ W2f, _Float16* __restrict__ W3f,
    const int* __restrict__ edge_index, int* __restrict__ cnt, int E)
{
    if (blockIdx.x >= nbPre + 144) {
        int e = (blockIdx.x - nbPre - 144) * 256 + threadIdx.x;
        if (e < E) atomicAdd(&cnt[edge_index[e]], 1);
        return;
    }
    if (blockIdx.x >= nbPre) {
        int id = (blockIdx.x - nbPre) * 256 + threadIdx.x;
        if (id < 4096) {
            int i = id & 7, l = (id >> 3) & 63, t = id >> 9;    // t in 0..7
            int s = t >> 2, nt = t & 3;
            int k = s * 32 + (l >> 4) * 8 + i;
            int n = nt * 16 + (l & 15);
            W1f[id] = (k < 48) ? (_Float16)Ws1[k * 64 + n] : (_Float16)0.f;
        } else if (id < 4096 + 8192) {
            int j = id - 4096;
            int i = j & 7, l = (j >> 3) & 63, t = j >> 9;       // t in 0..15
            int s = t >> 3, nt = t & 7;
            int k = s * 32 + (l >> 4) * 8 + i;
            int n = nt * 16 + (l & 15);
            W2f[j] = (_Float16)Ws2[k * 128 + n];
        } else if (id < 4096 + 8192 + 24576) {
            int j = id - 4096 - 8192;
            int i = j & 7, l = (j >> 3) & 63, t = j >> 9;       // t in 0..47
            int s = t / 12, nt = t % 12;
            int k = s * 32 + (l >> 4) * 8 + i;
            int n = nt * 16 + (l & 15);
            W3f[j] = (_Float16)Ws3[k * 192 + n];
        }
        return;
    }

    int sub = threadIdx.x >> 6;
    int h = threadIdx.x & 63;
    int n = blockIdx.x * 4 + sub;
    int nn = (n < N) ? n : (N - 1);

    const float* Xb = X + (size_t)nn * 9 * HD + h;
    float x[9];
    float nrm = 0.f;
#pragma unroll
    for (int i = 0; i < 9; ++i) { x[i] = Xb[i * HD]; nrm += x[i] * x[i]; }
    float inv = 1.0f / (nrm + 1.0f);
#pragma unroll
    for (int i = 0; i < 9; ++i) x[i] *= inv;

    float I0 = (x[0] + x[4] + x[8]) * (1.0f / 3.0f);
    __shared__ float comp[4][10][HD];
    comp[sub][0][h] = I0;
    comp[sub][1][h] = 0.5f * (x[1] - x[3]);
    comp[sub][2][h] = 0.5f * (x[2] - x[6]);
    comp[sub][3][h] = 0.5f * (x[5] - x[7]);
    comp[sub][4][h] = x[0] - I0;
    comp[sub][5][h] = 0.5f * (x[1] + x[3]);
    comp[sub][6][h] = 0.5f * (x[2] + x[6]);
    comp[sub][7][h] = x[4] - I0;
    comp[sub][8][h] = 0.5f * (x[5] + x[7]);
    comp[sub][9][h] = x[8] - I0;
    __syncthreads();
    float acc[10];
#pragma unroll
    for (int i = 0; i < 10; ++i) acc[i] = 0.f;
    for (int k = 0; k < HD; ++k) {
        float w0 = Wt0[k * HD + h];
        float w1 = Wt1[k * HD + h];
        float w2 = Wt2[k * HD + h];
        acc[0] += comp[sub][0][k] * w0;
        acc[1] += comp[sub][1][k] * w1;
        acc[2] += comp[sub][2][k] * w1;
        acc[3] += comp[sub][3][k] * w1;
#pragma unroll
        for (int j = 0; j < 6; ++j) acc[4 + j] += comp[sub][4 + j][k] * w2;
    }
    if (n < N) {
        float* tp = Tn + (size_t)n * 640 + h;
        _Float16* th = TnH + (size_t)n * 640 + h;
#pragma unroll
        for (int i = 0; i < 10; ++i) {
            tp[i * 64] = acc[i];
            th[i * 64] = (_Float16)acc[i];
        }
    }
}

// ---------------- single-block scan (N<=64K): offs + curs + offs[N] ----------
__global__ __launch_bounds__(1024) void scan_kernel(
    const int* __restrict__ cnt, int* __restrict__ offs, int* __restrict__ curs, int N)
{
    __shared__ int partials[16];
    __shared__ int base_s;
    int tid = threadIdx.x, wid = tid >> 6, lane = tid & 63;
    if (tid == 0) base_s = 0;
    __syncthreads();
    for (int start = 0; start < N; start += 1024) {
        int i = start + tid;
        int v = (i < N) ? cnt[i] : 0;
        int s = v;
#pragma unroll
        for (int d = 1; d < 64; d <<= 1) {
            int t = __shfl_up(s, d, 64);
            if (lane >= d) s += t;
        }
        if (lane == 63) partials[wid] = s;
        __syncthreads();
        if (tid == 0) {
            int run = base_s;
#pragma unroll
            for (int w = 0; w < 16; ++w) { int t = partials[w]; partials[w] = run; run += t; }
            base_s = run;
        }
        __syncthreads();
        int excl = partials[wid] + s - v;
        if (i < N) { offs[i] = excl; curs[i] = excl; }
        __syncthreads();
    }
    if (tid == 0) offs[N] = base_s;
}

// ---------------- fused MLP via MFMA fp16 — column-split + inline place ------
// Round-21 best structure: 4 waves share 64 edges in one LDS tile; wave owns
// a column slice per layer; inline CSR place in staging lane.
__global__ __launch_bounds__(256, 5) void mlp_mfma(
    const float* __restrict__ edge_attr, const float* __restrict__ charges,
    const float* __restrict__ edge_weight, const int* __restrict__ edge_index,
    int* __restrict__ curs, int* __restrict__ colP,
    const _Float16* __restrict__ W1f, const float* __restrict__ bs1,
    const _Float16* __restrict__ W2f, const float* __restrict__ bs2,
    const _Float16* __restrict__ W3f, const float* __restrict__ bs3,
    _Float16* __restrict__ bufH, int E)
{
    __shared__ __align__(16) _Float16 act[64][200];
    __shared__ float cvsS[64];
    __shared__ int rankSS[64];

    int tid = threadIdx.x;
    int wv = tid >> 6, l = tid & 63;
    int base = blockIdx.x * 64;
    int row16 = l & 15, quad = l >> 4;

    // ---- block staging: 64 edges x 16 float4-slots, 4 per thread ----
#pragma unroll
    for (int i = 0; i < 4; ++i) {
        int slot = tid + i * 256;
        int e_l = slot >> 4, f = slot & 15;
        int e = base + e_l;
        int ee = (e < E) ? e : (E - 1);
        float4 v = make_float4(0.f, 0.f, 0.f, 0.f);
        if (f < 8) {
            v = *(const float4*)(edge_attr + (size_t)ee * 32 + f * 4);
        } else if (f < 10) {
            int r = edge_index[ee];
            v = *(const float4*)(charges + (size_t)r * 8 + (f - 8) * 4);
        } else if (f < 12) {
            int c = edge_index[E + ee];
            v = *(const float4*)(charges + (size_t)c * 8 + (f - 10) * 4);
        }
        half4v hv = { (_Float16)v.x, (_Float16)v.y, (_Float16)v.z, (_Float16)v.w };
        *(half4v*)&act[e_l][f * 4] = hv;
    }
    if (tid < 64) {
        int e = base + tid;
        bool valid = (e < E);
        int ee = valid ? e : (E - 1);
        int row = edge_index[ee];
        int col = edge_index[E + ee];
        int rk = 0;
        if (valid) {
            rk = atomicAdd(&curs[row], 1);
            colP[rk] = col;
        }
        rankSS[tid] = rk;
        float wgt = edge_weight[ee];
        float cv = 0.5f * (__cosf(wgt * 0.6283185307179586f) + 1.0f);
        cvsS[tid] = (wgt < 5.0f) ? cv : 0.0f;
    }
    __syncthreads();

    // ---- layer 1: wave computes nt=wv for all 4 tiles -> h1 at [128,192) ----
    {
        half8 w0 = *(const half8*)(W1f + ((size_t)(0 * 4 + wv) * 64 + l) * 8);
        half8 w1 = *(const half8*)(W1f + ((size_t)(1 * 4 + wv) * 64 + l) * 8);
        floatx4 acc1[4];
#pragma unroll
        for (int m = 0; m < 4; ++m) {
            floatx4 c = {0.f, 0.f, 0.f, 0.f};
            c = __builtin_amdgcn_mfma_f32_16x16x32_f16(
                    *(const half8*)&act[m * 16 + row16][quad * 8], w0, c, 0, 0, 0);
            c = __builtin_amdgcn_mfma_f32_16x16x32_f16(
                    *(const half8*)&act[m * 16 + row16][32 + quad * 8], w1, c, 0, 0, 0);
            acc1[m] = c;
        }
        float b = bs1[wv * 16 + row16];
#pragma unroll
        for (int m = 0; m < 4; ++m)
#pragma unroll
            for (int r = 0; r < 4; ++r)
                act[m * 16 + quad * 4 + r][128 + wv * 16 + row16] =
                    (_Float16)silu_f(acc1[m][r] + b);
    }
    __syncthreads();

    // ---- layer 2: wave computes nt=wv*2+j (j=0,1) -> h2 at [0,128) ----
    {
        floatx4 acc2[4][2];
#pragma unroll
        for (int m = 0; m < 4; ++m)
#pragma unroll
            for (int j = 0; j < 2; ++j) acc2[m][j] = (floatx4){0.f, 0.f, 0.f, 0.f};
#pragma unroll
        for (int s = 0; s < 2; ++s) {
            half8 w0 = *(const half8*)(W2f + ((size_t)(s * 8 + wv * 2 + 0) * 64 + l) * 8);
            half8 w1 = *(const half8*)(W2f + ((size_t)(s * 8 + wv * 2 + 1) * 64 + l) * 8);
#pragma unroll
            for (int m = 0; m < 4; ++m) {
                half8 a = *(const half8*)&act[m * 16 + row16][128 + s * 32 + quad * 8];
                acc2[m][0] = __builtin_amdgcn_mfma_f32_16x16x32_f16(a, w0, acc2[m][0], 0, 0, 0);
                acc2[m][1] = __builtin_amdgcn_mfma_f32_16x16x32_f16(a, w1, acc2[m][1], 0, 0, 0);
            }
        }
        float b0 = bs2[(wv * 2 + 0) * 16 + row16];
        float b1 = bs2[(wv * 2 + 1) * 16 + row16];
#pragma unroll
        for (int m = 0; m < 4; ++m)
#pragma unroll
            for (int r = 0; r < 4; ++r) {
                act[m * 16 + quad * 4 + r][(wv * 2 + 0) * 16 + row16] =
                    (_Float16)silu_f(acc2[m][0][r] + b0);
                act[m * 16 + quad * 4 + r][(wv * 2 + 1) * 16 + row16] =
                    (_Float16)silu_f(acc2[m][1][r] + b1);
            }
    }
    __syncthreads();

    // ---- layer 3: wave computes nt=wv*3+j (j=0..2), all in regs ----
    floatx4 acc3[4][3];
#pragma unroll
    for (int m = 0; m < 4; ++m)
#pragma unroll
        for (int j = 0; j < 3; ++j) acc3[m][j] = (floatx4){0.f, 0.f, 0.f, 0.f};
#pragma unroll
    for (int s = 0; s < 4; ++s) {
        half8 w0 = *(const half8*)(W3f + ((size_t)(s * 12 + wv * 3 + 0) * 64 + l) * 8);
        half8 w1 = *(const half8*)(W3f + ((size_t)(s * 12 + wv * 3 + 1) * 64 + l) * 8);
        half8 w2 = *(const half8*)(W3f + ((size_t)(s * 12 + wv * 3 + 2) * 64 + l) * 8);
#pragma unroll
        for (int m = 0; m < 4; ++m) {
            half8 a = *(const half8*)&act[m * 16 + row16][s * 32 + quad * 8];
            acc3[m][0] = __builtin_amdgcn_mfma_f32_16x16x32_f16(a, w0, acc3[m][0], 0, 0, 0);
            acc3[m][1] = __builtin_amdgcn_mfma_f32_16x16x32_f16(a, w1, acc3[m][1], 0, 0, 0);
            acc3[m][2] = __builtin_amdgcn_mfma_f32_16x16x32_f16(a, w2, acc3[m][2], 0, 0, 0);
        }
    }
    __syncthreads();   // all h2 reads done -> safe to park w over [0,192)

    {
        float b0 = bs3[(wv * 3 + 0) * 16 + row16];
        float b1 = bs3[(wv * 3 + 1) * 16 + row16];
        float b2 = bs3[(wv * 3 + 2) * 16 + row16];
#pragma unroll
        for (int m = 0; m < 4; ++m) {
#pragma unroll
            for (int r = 0; r < 4; ++r) {
                float cv = cvsS[m * 16 + quad * 4 + r];
                act[m * 16 + quad * 4 + r][(wv * 3 + 0) * 16 + row16] =
                    (_Float16)(silu_f(acc3[m][0][r] + b0) * cv);
                act[m * 16 + quad * 4 + r][(wv * 3 + 1) * 16 + row16] =
                    (_Float16)(silu_f(acc3[m][1][r] + b1) * cv);
                act[m * 16 + quad * 4 + r][(wv * 3 + 2) * 16 + row16] =
                    (_Float16)(silu_f(acc3[m][2][r] + b2) * cv);
            }
        }
    }
    __syncthreads();

    // ---- coalesced flush: 256 thr, 4 lanes per row, 64 rows ----
    {
        int fr = tid >> 2;
        int ef = base + fr;
        if (ef < E) {
            _Float16* dst = bufH + (size_t)rankSS[fr] * 192;
#pragma unroll
            for (int i = 0; i < 6; ++i) {
                int j = (tid & 3) + i * 4;
                *(half8*)(dst + j * 8) = *(const half8*)&act[fr][j * 8];
            }
        }
    }
}

// ---------------- msg kernel: 1 node/block, 4-way edge split, fp16 Mn --------
__global__ __launch_bounds__(256) void msg_kernel(
    const _Float16* __restrict__ bufH, const int* __restrict__ colP,
    const int* __restrict__ offs, const _Float16* __restrict__ TnH,
    _Float16* __restrict__ MnH, int N)
{
    __shared__ float part[4][10][64];
    int qtr = threadIdx.x >> 6;
    int lane = threadIdx.x & 63;
    int n = blockIdx.x;
    int beg = offs[n], end = offs[n + 1];
    int len = end - beg;
    int s0 = beg + (len * qtr) / 4;
    int s1 = beg + (len * (qtr + 1)) / 4;

    float a0 = 0.f, a1 = 0.f, a2 = 0.f, a3 = 0.f, a4 = 0.f;
    float a5 = 0.f, a6 = 0.f, a7 = 0.f, a8 = 0.f, a9 = 0.f;
#pragma unroll 2
    for (int idx = s0; idx < s1; ++idx) {
        int c = colP[idx];
        const _Float16* wp = bufH + (size_t)idx * 192;
        float w0 = (float)wp[lane];
        float w1 = (float)wp[64 + lane];
        float w2 = (float)wp[128 + lane];
        const _Float16* tp = TnH + (size_t)c * 640;
        a0 += w0 * (float)tp[lane];
        a1 += w1 * (float)tp[64 + lane];
        a2 += w1 * (float)tp[128 + lane];
        a3 += w1 * (float)tp[192 + lane];
        a4 += w2 * (float)tp[256 + lane];
        a5 += w2 * (float)tp[320 + lane];
        a6 += w2 * (float)tp[384 + lane];
        a7 += w2 * (float)tp[448 + lane];
        a8 += w2 * (float)tp[512 + lane];
        a9 += w2 * (float)tp[576 + lane];
    }
    part[qtr][0][lane] = a0; part[qtr][1][lane] = a1;
    part[qtr][2][lane] = a2; part[qtr][3][lane] = a3;
    part[qtr][4][lane] = a4; part[qtr][5][lane] = a5;
    part[qtr][6][lane] = a6; part[qtr][7][lane] = a7;
    part[qtr][8][lane] = a8; part[qtr][9][lane] = a9;
    __syncthreads();

    if (qtr < 2) {
        _Float16* mp = MnH + (size_t)n * 640;
#pragma unroll
        for (int j = 0; j < 5; ++j) {
            int c = qtr * 5 + j;
            mp[c * 64 + lane] = (_Float16)((part[0][c][lane] + part[1][c][lane])
                                         + (part[2][c][lane] + part[3][c][lane]));
        }
    }
}

// ---------------- node_post: 4 nodes/block (256 thr) -------------------------
__global__ __launch_bounds__(256) void node_post(
    const float* __restrict__ X,
    const float* __restrict__ Tn, const _Float16* __restrict__ MnH,
    const float* __restrict__ Wt3, const float* __restrict__ Wt4, const float* __restrict__ Wt5,
    float* __restrict__ out, int N)
{
    int sub = threadIdx.x >> 6;
    int h = threadIdx.x & 63;
    int n = blockIdx.x * 4 + sub;
    int nn = (n < N) ? n : (N - 1);

    const float* Xb = X + (size_t)nn * 9 * HD + h;
    float x[9];
    float nr = 0.f;
#pragma unroll
    for (int i = 0; i < 9; ++i) { x[i] = Xb[i * HD]; nr += x[i] * x[i]; }
    float xinv = 1.0f / (nr + 1.0f);
#pragma unroll
    for (int i = 0; i < 9; ++i) x[i] *= xinv;

    const float* tp = Tn + (size_t)nn * 640 + h;
    const _Float16* mp = MnH + (size_t)nn * 640 + h;
    float yI = tp[0], mI = (float)mp[0];
    float yA[3], yS[6], mA[3], mS[6];
#pragma unroll
    for (int j = 0; j < 3; ++j) { yA[j] = tp[(1 + j) * 64]; mA[j] = (float)mp[(1 + j) * 64]; }
#pragma unroll
    for (int j = 0; j < 6; ++j) { yS[j] = tp[(4 + j) * 64]; mS[j] = (float)mp[(4 + j) * 64]; }

    float M[3][3] = {
        { mI + mS[0],     mA[0] + mS[1],   mA[1] + mS[2] },
        { -mA[0] + mS[1], mI + mS[3],      mA[2] + mS[4] },
        { -mA[1] + mS[2], -mA[2] + mS[4],  mI + mS[5] } };
    float Y[3][3] = {
        { yI + yS[0],     yA[0] + yS[1],   yA[1] + yS[2] },
        { -yA[0] + yS[1], yI + yS[3],      yA[2] + yS[4] },
        { -yA[1] + yS[2], -yA[2] + yS[4],  yI + yS[5] } };

    float Cm[3][3];
    float nrm = 0.f;
#pragma unroll
    for (int a = 0; a < 3; ++a) {
#pragma unroll
        for (int b = 0; b < 3; ++b) {
            float s = 0.f;
#pragma unroll
            for (int c = 0; c < 3; ++c) s += M[a][c] * Y[c][b] + Y[a][c] * M[c][b];
            Cm[a][b] = s;
            nrm += s * s;
        }
    }
    float inv = 1.0f / (nrm + 1.0f);
    float tr3 = (Cm[0][0] + Cm[1][1] + Cm[2][2]) * (1.0f / 3.0f);

    __shared__ float comp[4][10][HD];
    comp[sub][0][h] = tr3 * inv;
    comp[sub][1][h] = 0.5f * (Cm[0][1] - Cm[1][0]) * inv;
    comp[sub][2][h] = 0.5f * (Cm[0][2] - Cm[2][0]) * inv;
    comp[sub][3][h] = 0.5f * (Cm[1][2] - Cm[2][1]) * inv;
    comp[sub][4][h] = (Cm[0][0] - tr3) * inv;
    comp[sub][5][h] = 0.5f * (Cm[0][1] + Cm[1][0]) * inv;
    comp[sub][6][h] = 0.5f * (Cm[0][2] + Cm[2][0]) * inv;
    comp[sub][7][h] = (Cm[1][1] - tr3) * inv;
    comp[sub][8][h] = 0.5f * (Cm[1][2] + Cm[2][1]) * inv;
    comp[sub][9][h] = (Cm[2][2] - tr3) * inv;
    __syncthreads();

    float acc[10];
#pragma unroll
    for (int i = 0; i < 10; ++i) acc[i] = 0.f;
    for (int k = 0; k < HD; ++k) {
        float w3 = Wt3[k * HD + h];
        float w4 = Wt4[k * HD + h];
        float w5 = Wt5[k * HD + h];
        acc[0] += comp[sub][0][k] * w3;
        acc[1] += comp[sub][1][k] * w4;
        acc[2] += comp[sub][2][k] * w4;
        acc[3] += comp[sub][3][k] * w4;
#pragma unroll
        for (int j = 0; j < 6; ++j) acc[4 + j] += comp[sub][4 + j][k] * w5;
    }
    float D[3][3] = {
        { acc[0] + acc[4],  acc[1] + acc[5],  acc[2] + acc[6] },
        { -acc[1] + acc[5], acc[0] + acc[7],  acc[3] + acc[8] },
        { -acc[2] + acc[6], -acc[3] + acc[8], acc[0] + acc[9] } };

    if (n < N) {
        float* ob = out + (size_t)n * 9 * HD + h;
#pragma unroll
        for (int a = 0; a < 3; ++a) {
#pragma unroll
            for (int b = 0; b < 3; ++b) {
                float s = 0.f;
#pragma unroll
                for (int c = 0; c < 3; ++c) s += D[a][c] * D[c][b];
                ob[(a * 3 + b) * HD] = x[a * 3 + b] + D[a][b] + s;
            }
        }
    }
}

// ---------------- launch ------------------------------------------------------
extern "C" void kernel_launch(void* const* d_in, const int* in_sizes, int n_in,
                              void* d_out, int out_size, void* d_ws, size_t ws_size,
                              hipStream_t stream)
{
    const float* X           = (const float*)d_in[0];
    const float* charges     = (const float*)d_in[1];
    const float* edge_weight = (const float*)d_in[2];
    const float* edge_attr   = (const float*)d_in[3];
    const int*   edge_index  = (const int*)d_in[4];
    const float* Ws1 = (const float*)d_in[5];
    const float* bs1 = (const float*)d_in[6];
    const float* Ws2 = (const float*)d_in[7];
    const float* bs2 = (const float*)d_in[8];
    const float* Ws3 = (const float*)d_in[9];
    const float* bs3 = (const float*)d_in[10];
    const float* Wt0 = (const float*)d_in[11];
    const float* Wt1 = (const float*)d_in[12];
    const float* Wt2 = (const float*)d_in[13];
    const float* Wt3 = (const float*)d_in[14];
    const float* Wt4 = (const float*)d_in[15];
    const float* Wt5 = (const float*)d_in[16];

    int N = in_sizes[0] / (9 * HD);
    int E = in_sizes[2];

    float* ws = (float*)d_ws;
    float* Tn  = ws;                                   // N*640 f32
    _Float16* TnH  = (_Float16*)(Tn + (size_t)N * 640);   // N*640 f16
    _Float16* MnH  = TnH + (size_t)N * 640;               // N*640 f16
    _Float16* bufH = MnH + (size_t)N * 640;               // E*192 f16 (CSR slots)
    int* cnt   = (int*)(bufH + (size_t)E * 192);       // N
    int* offs  = cnt + N;                              // N+1
    int* curs  = offs + N + 1;                         // N
    int* colP  = curs + N;                             // E
    size_t fofs = ((size_t)((char*)(colP + E) - (char*)d_ws) + 15) & ~(size_t)15;
    _Float16* W1f = (_Float16*)((char*)d_ws + fofs);   // 4096
    _Float16* W2f = W1f + 4096;                        // 8192
    _Float16* W3f = W2f + 8192;                        // 24576

    hipMemsetAsync(cnt, 0, (size_t)N * sizeof(int), stream);

    int nbPre = (N + 3) / 4;
    int nbE256 = (E + 255) / 256;
    pre_wconv_count<<<nbPre + 144 + nbE256, 256, 0, stream>>>(
        X, Wt0, Wt1, Wt2, Tn, TnH, N, nbPre,
        Ws1, Ws2, Ws3, W1f, W2f, W3f, edge_index, cnt, E);

    scan_kernel<<<1, 1024, 0, stream>>>(cnt, offs, curs, N);

    int nbE64 = (E + 63) / 64;
    mlp_mfma<<<nbE64, 256, 0, stream>>>(edge_attr, charges, edge_weight, edge_index,
                                        curs, colP, W1f, bs1, W2f, bs2, W3f, bs3, bufH, E);

    msg_kernel<<<N, 256, 0, stream>>>(bufH, colP, offs, TnH, MnH, N);

    node_post<<<(N + 3) / 4, 256, 0, stream>>>(X, Tn, MnH, Wt3, Wt4, Wt5, (float*)d_out, N);
}

// Round 24
// 154.269 us; speedup vs baseline: 1.1420x; 1.0155x over previous
//
#include <hip/hip_runtime.h>
#include <math.h>

#define HD 64

typedef _Float16 half8 __attribute__((ext_vector_type(8)));
typedef _Float16 half4v __attribute__((ext_vector_type(4)));
typedef float floatx4 __attribute__((ext_vector_type(4)));

__device__ __forceinline__ float silu_f(float x) {
    return x * __builtin_amdgcn_rcpf(1.0f + __expf(-x));
}

// ------- pre_wconv_count: node_pre blocks | wconv blocks | count blocks ------
__global__ __launch_bounds__(256) void pre_wconv_count(
    const float* __restrict__ X,
    const float* __restrict__ Wt0, const float* __restrict__ Wt1, const float* __restrict__ Wt2,
    _Float16* __restrict__ TnH, int N, int nbPre,
    const float* __restrict__ Ws1, const float* __restrict__ Ws2, const float* __restrict__ Ws3,
    _Float16* __restrict__ W1f, _Float16* __restrict__ W2f, _Float16* __restrict__ W3f,
    const int* __restrict__ edge_index, int* __restrict__ cnt, int E)
{
    if (blockIdx.x >= nbPre + 144) {
        int e = (blockIdx.x - nbPre - 144) * 256 + threadIdx.x;
        if (e < E) atomicAdd(&cnt[edge_index[e]], 1);
        return;
    }
    if (blockIdx.x >= nbPre) {
        int id = (blockIdx.x - nbPre) * 256 + threadIdx.x;
        if (id < 4096) {
            int i = id & 7, l = (id >> 3) & 63, t = id >> 9;    // t in 0..7
            int s = t >> 2, nt = t & 3;
            int k = s * 32 + (l >> 4) * 8 + i;
            int n = nt * 16 + (l & 15);
            W1f[id] = (k < 48) ? (_Float16)Ws1[k * 64 + n] : (_Float16)0.f;
        } else if (id < 4096 + 8192) {
            int j = id - 4096;
            int i = j & 7, l = (j >> 3) & 63, t = j >> 9;       // t in 0..15
            int s = t >> 3, nt = t & 7;
            int k = s * 32 + (l >> 4) * 8 + i;
            int n = nt * 16 + (l & 15);
            W2f[j] = (_Float16)Ws2[k * 128 + n];
        } else if (id < 4096 + 8192 + 24576) {
            int j = id - 4096 - 8192;
            int i = j & 7, l = (j >> 3) & 63, t = j >> 9;       // t in 0..47
            int s = t / 12, nt = t % 12;
            int k = s * 32 + (l >> 4) * 8 + i;
            int n = nt * 16 + (l & 15);
            W3f[j] = (_Float16)Ws3[k * 192 + n];
        }
        return;
    }

    int sub = threadIdx.x >> 6;
    int h = threadIdx.x & 63;
    int n = blockIdx.x * 4 + sub;
    int nn = (n < N) ? n : (N - 1);

    const float* Xb = X + (size_t)nn * 9 * HD + h;
    float x[9];
    float nrm = 0.f;
#pragma unroll
    for (int i = 0; i < 9; ++i) { x[i] = Xb[i * HD]; nrm += x[i] * x[i]; }
    float inv = 1.0f / (nrm + 1.0f);
#pragma unroll
    for (int i = 0; i < 9; ++i) x[i] *= inv;

    float I0 = (x[0] + x[4] + x[8]) * (1.0f / 3.0f);
    __shared__ float comp[4][10][HD];
    comp[sub][0][h] = I0;
    comp[sub][1][h] = 0.5f * (x[1] - x[3]);
    comp[sub][2][h] = 0.5f * (x[2] - x[6]);
    comp[sub][3][h] = 0.5f * (x[5] - x[7]);
    comp[sub][4][h] = x[0] - I0;
    comp[sub][5][h] = 0.5f * (x[1] + x[3]);
    comp[sub][6][h] = 0.5f * (x[2] + x[6]);
    comp[sub][7][h] = x[4] - I0;
    comp[sub][8][h] = 0.5f * (x[5] + x[7]);
    comp[sub][9][h] = x[8] - I0;
    __syncthreads();
    float acc[10];
#pragma unroll
    for (int i = 0; i < 10; ++i) acc[i] = 0.f;
    for (int k = 0; k < HD; ++k) {
        float w0 = Wt0[k * HD + h];
        float w1 = Wt1[k * HD + h];
        float w2 = Wt2[k * HD + h];
        acc[0] += comp[sub][0][k] * w0;
        acc[1] += comp[sub][1][k] * w1;
        acc[2] += comp[sub][2][k] * w1;
        acc[3] += comp[sub][3][k] * w1;
#pragma unroll
        for (int j = 0; j < 6; ++j) acc[4 + j] += comp[sub][4 + j][k] * w2;
    }
    if (n < N) {
        _Float16* th = TnH + (size_t)n * 640 + h;
#pragma unroll
        for (int i = 0; i < 10; ++i)
            th[i * 64] = (_Float16)acc[i];
    }
}

// ---------------- single-block scan (N<=64K): offs + curs + offs[N] ----------
__global__ __launch_bounds__(1024) void scan_kernel(
    const int* __restrict__ cnt, int* __restrict__ offs, int* __restrict__ curs, int N)
{
    __shared__ int partials[16];
    __shared__ int base_s;
    int tid = threadIdx.x, wid = tid >> 6, lane = tid & 63;
    if (tid == 0) base_s = 0;
    __syncthreads();
    for (int start = 0; start < N; start += 1024) {
        int i = start + tid;
        int v = (i < N) ? cnt[i] : 0;
        int s = v;
#pragma unroll
        for (int d = 1; d < 64; d <<= 1) {
            int t = __shfl_up(s, d, 64);
            if (lane >= d) s += t;
        }
        if (lane == 63) partials[wid] = s;
        __syncthreads();
        if (tid == 0) {
            int run = base_s;
#pragma unroll
            for (int w = 0; w < 16; ++w) { int t = partials[w]; partials[w] = run; run += t; }
            base_s = run;
        }
        __syncthreads();
        int excl = partials[wid] + s - v;
        if (i < N) { offs[i] = excl; curs[i] = excl; }
        __syncthreads();
    }
    if (tid == 0) offs[N] = base_s;
}

// ---------------- fused MLP via MFMA fp16 — column-split + inline place ------
__global__ __launch_bounds__(256, 6) void mlp_mfma(
    const float* __restrict__ edge_attr, const float* __restrict__ charges,
    const float* __restrict__ edge_weight, const int* __restrict__ edge_index,
    int* __restrict__ curs, int* __restrict__ colP,
    const _Float16* __restrict__ W1f, const float* __restrict__ bs1,
    const _Float16* __restrict__ W2f, const float* __restrict__ bs2,
    const _Float16* __restrict__ W3f, const float* __restrict__ bs3,
    _Float16* __restrict__ bufH, int E)
{
    __shared__ __align__(16) _Float16 act[64][200];
    __shared__ float cvsS[64];
    __shared__ int rankSS[64];

    int tid = threadIdx.x;
    int wv = tid >> 6, l = tid & 63;
    int base = blockIdx.x * 64;
    int row16 = l & 15, quad = l >> 4;

    // ---- block staging: 64 edges x 16 float4-slots, 4 per thread ----
#pragma unroll
    for (int i = 0; i < 4; ++i) {
        int slot = tid + i * 256;
        int e_l = slot >> 4, f = slot & 15;
        int e = base + e_l;
        int ee = (e < E) ? e : (E - 1);
        float4 v = make_float4(0.f, 0.f, 0.f, 0.f);
        if (f < 8) {
            v = *(const float4*)(edge_attr + (size_t)ee * 32 + f * 4);
        } else if (f < 10) {
            int r = edge_index[ee];
            v = *(const float4*)(charges + (size_t)r * 8 + (f - 8) * 4);
        } else if (f < 12) {
            int c = edge_index[E + ee];
            v = *(const float4*)(charges + (size_t)c * 8 + (f - 10) * 4);
        }
        half4v hv = { (_Float16)v.x, (_Float16)v.y, (_Float16)v.z, (_Float16)v.w };
        *(half4v*)&act[e_l][f * 4] = hv;
    }
    if (tid < 64) {
        int e = base + tid;
        bool valid = (e < E);
        int ee = valid ? e : (E - 1);
        int row = edge_index[ee];
        int col = edge_index[E + ee];
        int rk = 0;
        if (valid) {
            rk = atomicAdd(&curs[row], 1);
            colP[rk] = col;
        }
        rankSS[tid] = rk;
        float wgt = edge_weight[ee];
        float cv = 0.5f * (__cosf(wgt * 0.6283185307179586f) + 1.0f);
        cvsS[tid] = (wgt < 5.0f) ? cv : 0.0f;
    }
    __syncthreads();

    // ---- layer 1: wave computes nt=wv for all 4 tiles -> h1 at [128,192) ----
    {
        half8 w0 = *(const half8*)(W1f + ((size_t)(0 * 4 + wv) * 64 + l) * 8);
        half8 w1 = *(const half8*)(W1f + ((size_t)(1 * 4 + wv) * 64 + l) * 8);
        floatx4 acc1[4];
#pragma unroll
        for (int m = 0; m < 4; ++m) {
            floatx4 c = {0.f, 0.f, 0.f, 0.f};
            c = __builtin_amdgcn_mfma_f32_16x16x32_f16(
                    *(const half8*)&act[m * 16 + row16][quad * 8], w0, c, 0, 0, 0);
            c = __builtin_amdgcn_mfma_f32_16x16x32_f16(
                    *(const half8*)&act[m * 16 + row16][32 + quad * 8], w1, c, 0, 0, 0);
            acc1[m] = c;
        }
        float b = bs1[wv * 16 + row16];
#pragma unroll
        for (int m = 0; m < 4; ++m)
#pragma unroll
            for (int r = 0; r < 4; ++r)
                act[m * 16 + quad * 4 + r][128 + wv * 16 + row16] =
                    (_Float16)silu_f(acc1[m][r] + b);
    }
    __syncthreads();

    // ---- layer 2: wave computes nt=wv*2+j (j=0,1) -> h2 at [0,128) ----
    {
        floatx4 acc2[4][2];
#pragma unroll
        for (int m = 0; m < 4; ++m)
#pragma unroll
            for (int j = 0; j < 2; ++j) acc2[m][j] = (floatx4){0.f, 0.f, 0.f, 0.f};
#pragma unroll
        for (int s = 0; s < 2; ++s) {
            half8 w0 = *(const half8*)(W2f + ((size_t)(s * 8 + wv * 2 + 0) * 64 + l) * 8);
            half8 w1 = *(const half8*)(W2f + ((size_t)(s * 8 + wv * 2 + 1) * 64 + l) * 8);
#pragma unroll
            for (int m = 0; m < 4; ++m) {
                half8 a = *(const half8*)&act[m * 16 + row16][128 + s * 32 + quad * 8];
                acc2[m][0] = __builtin_amdgcn_mfma_f32_16x16x32_f16(a, w0, acc2[m][0], 0, 0, 0);
                acc2[m][1] = __builtin_amdgcn_mfma_f32_16x16x32_f16(a, w1, acc2[m][1], 0, 0, 0);
            }
        }
        float b0 = bs2[(wv * 2 + 0) * 16 + row16];
        float b1 = bs2[(wv * 2 + 1) * 16 + row16];
#pragma unroll
        for (int m = 0; m < 4; ++m)
#pragma unroll
            for (int r = 0; r < 4; ++r) {
                act[m * 16 + quad * 4 + r][(wv * 2 + 0) * 16 + row16] =
                    (_Float16)silu_f(acc2[m][0][r] + b0);
                act[m * 16 + quad * 4 + r][(wv * 2 + 1) * 16 + row16] =
                    (_Float16)silu_f(acc2[m][1][r] + b1);
            }
    }
    __syncthreads();

    // ---- layer 3: wave computes nt=wv*3+j (j=0..2), all in regs ----
    floatx4 acc3[4][3];
#pragma unroll
    for (int m = 0; m < 4; ++m)
#pragma unroll
        for (int j = 0; j < 3; ++j) acc3[m][j] = (floatx4){0.f, 0.f, 0.f, 0.f};
#pragma unroll
    for (int s = 0; s < 4; ++s) {
        half8 w0 = *(const half8*)(W3f + ((size_t)(s * 12 + wv * 3 + 0) * 64 + l) * 8);
        half8 w1 = *(const half8*)(W3f + ((size_t)(s * 12 + wv * 3 + 1) * 64 + l) * 8);
        half8 w2 = *(const half8*)(W3f + ((size_t)(s * 12 + wv * 3 + 2) * 64 + l) * 8);
#pragma unroll
        for (int m = 0; m < 4; ++m) {
            half8 a = *(const half8*)&act[m * 16 + row16][s * 32 + quad * 8];
            acc3[m][0] = __builtin_amdgcn_mfma_f32_16x16x32_f16(a, w0, acc3[m][0], 0, 0, 0);
            acc3[m][1] = __builtin_amdgcn_mfma_f32_16x16x32_f16(a, w1, acc3[m][1], 0, 0, 0);
            acc3[m][2] = __builtin_amdgcn_mfma_f32_16x16x32_f16(a, w2, acc3[m][2], 0, 0, 0);
        }
    }
    __syncthreads();   // all h2 reads done -> safe to park w over [0,192)

    {
        float b0 = bs3[(wv * 3 + 0) * 16 + row16];
        float b1 = bs3[(wv * 3 + 1) * 16 + row16];
        float b2 = bs3[(wv * 3 + 2) * 16 + row16];
#pragma unroll
        for (int m = 0; m < 4; ++m) {
#pragma unroll
            for (int r = 0; r < 4; ++r) {
                float cv = cvsS[m * 16 + quad * 4 + r];
                act[m * 16 + quad * 4 + r][(wv * 3 + 0) * 16 + row16] =
                    (_Float16)(silu_f(acc3[m][0][r] + b0) * cv);
                act[m * 16 + quad * 4 + r][(wv * 3 + 1) * 16 + row16] =
                    (_Float16)(silu_f(acc3[m][1][r] + b1) * cv);
                act[m * 16 + quad * 4 + r][(wv * 3 + 2) * 16 + row16] =
                    (_Float16)(silu_f(acc3[m][2][r] + b2) * cv);
            }
        }
    }
    __syncthreads();

    // ---- coalesced flush: 256 thr, 4 lanes per row, 64 rows ----
    {
        int fr = tid >> 2;
        int ef = base + fr;
        if (ef < E) {
            _Float16* dst = bufH + (size_t)rankSS[fr] * 192;
#pragma unroll
            for (int i = 0; i < 6; ++i) {
                int j = (tid & 3) + i * 4;
                *(half8*)(dst + j * 8) = *(const half8*)&act[fr][j * 8];
            }
        }
    }
}

// ---------------- msg kernel: 1 node/block, 4-way edge split, fp16 Mn --------
__global__ __launch_bounds__(256) void msg_kernel(
    const _Float16* __restrict__ bufH, const int* __restrict__ colP,
    const int* __restrict__ offs, const _Float16* __restrict__ TnH,
    _Float16* __restrict__ MnH, int N)
{
    __shared__ float part[4][10][64];
    int qtr = threadIdx.x >> 6;
    int lane = threadIdx.x & 63;
    int n = blockIdx.x;
    int beg = offs[n], end = offs[n + 1];
    int len = end - beg;
    int s0 = beg + (len * qtr) / 4;
    int s1 = beg + (len * (qtr + 1)) / 4;

    float a0 = 0.f, a1 = 0.f, a2 = 0.f, a3 = 0.f, a4 = 0.f;
    float a5 = 0.f, a6 = 0.f, a7 = 0.f, a8 = 0.f, a9 = 0.f;
#pragma unroll 2
    for (int idx = s0; idx < s1; ++idx) {
        int c = colP[idx];
        const _Float16* wp = bufH + (size_t)idx * 192;
        float w0 = (float)wp[lane];
        float w1 = (float)wp[64 + lane];
        float w2 = (float)wp[128 + lane];
        const _Float16* tp = TnH + (size_t)c * 640;
        a0 += w0 * (float)tp[lane];
        a1 += w1 * (float)tp[64 + lane];
        a2 += w1 * (float)tp[128 + lane];
        a3 += w1 * (float)tp[192 + lane];
        a4 += w2 * (float)tp[256 + lane];
        a5 += w2 * (float)tp[320 + lane];
        a6 += w2 * (float)tp[384 + lane];
        a7 += w2 * (float)tp[448 + lane];
        a8 += w2 * (float)tp[512 + lane];
        a9 += w2 * (float)tp[576 + lane];
    }
    part[qtr][0][lane] = a0; part[qtr][1][lane] = a1;
    part[qtr][2][lane] = a2; part[qtr][3][lane] = a3;
    part[qtr][4][lane] = a4; part[qtr][5][lane] = a5;
    part[qtr][6][lane] = a6; part[qtr][7][lane] = a7;
    part[qtr][8][lane] = a8; part[qtr][9][lane] = a9;
    __syncthreads();

    if (qtr < 2) {
        _Float16* mp = MnH + (size_t)n * 640;
#pragma unroll
        for (int j = 0; j < 5; ++j) {
            int c = qtr * 5 + j;
            mp[c * 64 + lane] = (_Float16)((part[0][c][lane] + part[1][c][lane])
                                         + (part[2][c][lane] + part[3][c][lane]));
        }
    }
}

// ---------------- node_post: 4 nodes/block (256 thr), fp16 Tn/Mn -------------
__global__ __launch_bounds__(256) void node_post(
    const float* __restrict__ X,
    const _Float16* __restrict__ TnH, const _Float16* __restrict__ MnH,
    const float* __restrict__ Wt3, const float* __restrict__ Wt4, const float* __restrict__ Wt5,
    float* __restrict__ out, int N)
{
    int sub = threadIdx.x >> 6;
    int h = threadIdx.x & 63;
    int n = blockIdx.x * 4 + sub;
    int nn = (n < N) ? n : (N - 1);

    const float* Xb = X + (size_t)nn * 9 * HD + h;
    float x[9];
    float nr = 0.f;
#pragma unroll
    for (int i = 0; i < 9; ++i) { x[i] = Xb[i * HD]; nr += x[i] * x[i]; }
    float xinv = 1.0f / (nr + 1.0f);
#pragma unroll
    for (int i = 0; i < 9; ++i) x[i] *= xinv;

    const _Float16* tp = TnH + (size_t)nn * 640 + h;
    const _Float16* mp = MnH + (size_t)nn * 640 + h;
    float yI = (float)tp[0], mI = (float)mp[0];
    float yA[3], yS[6], mA[3], mS[6];
#pragma unroll
    for (int j = 0; j < 3; ++j) { yA[j] = (float)tp[(1 + j) * 64]; mA[j] = (float)mp[(1 + j) * 64]; }
#pragma unroll
    for (int j = 0; j < 6; ++j) { yS[j] = (float)tp[(4 + j) * 64]; mS[j] = (float)mp[(4 + j) * 64]; }

    float M[3][3] = {
        { mI + mS[0],     mA[0] + mS[1],   mA[1] + mS[2] },
        { -mA[0] + mS[1], mI + mS[3],      mA[2] + mS[4] },
        { -mA[1] + mS[2], -mA[2] + mS[4],  mI + mS[5] } };
    float Y[3][3] = {
        { yI + yS[0],     yA[0] + yS[1],   yA[1] + yS[2] },
        { -yA[0] + yS[1], yI + yS[3],      yA[2] + yS[4] },
        { -yA[1] + yS[2], -yA[2] + yS[4],  yI + yS[5] } };

    float Cm[3][3];
    float nrm = 0.f;
#pragma unroll
    for (int a = 0; a < 3; ++a) {
#pragma unroll
        for (int b = 0; b < 3; ++b) {
            float s = 0.f;
#pragma unroll
            for (int c = 0; c < 3; ++c) s += M[a][c] * Y[c][b] + Y[a][c] * M[c][b];
            Cm[a][b] = s;
            nrm += s * s;
        }
    }
    float inv = 1.0f / (nrm + 1.0f);
    float tr3 = (Cm[0][0] + Cm[1][1] + Cm[2][2]) * (1.0f / 3.0f);

    __shared__ float comp[4][10][HD];
    comp[sub][0][h] = tr3 * inv;
    comp[sub][1][h] = 0.5f * (Cm[0][1] - Cm[1][0]) * inv;
    comp[sub][2][h] = 0.5f * (Cm[0][2] - Cm[2][0]) * inv;
    comp[sub][3][h] = 0.5f * (Cm[1][2] - Cm[2][1]) * inv;
    comp[sub][4][h] = (Cm[0][0] - tr3) * inv;
    comp[sub][5][h] = 0.5f * (Cm[0][1] + Cm[1][0]) * inv;
    comp[sub][6][h] = 0.5f * (Cm[0][2] + Cm[2][0]) * inv;
    comp[sub][7][h] = (Cm[1][1] - tr3) * inv;
    comp[sub][8][h] = 0.5f * (Cm[1][2] + Cm[2][1]) * inv;
    comp[sub][9][h] = (Cm[2][2] - tr3) * inv;
    __syncthreads();

    float acc[10];
#pragma unroll
    for (int i = 0; i < 10; ++i) acc[i] = 0.f;
    for (int k = 0; k < HD; ++k) {
        float w3 = Wt3[k * HD + h];
        float w4 = Wt4[k * HD + h];
        float w5 = Wt5[k * HD + h];
        acc[0] += comp[sub][0][k] * w3;
        acc[1] += comp[sub][1][k] * w4;
        acc[2] += comp[sub][2][k] * w4;
        acc[3] += comp[sub][3][k] * w4;
#pragma unroll
        for (int j = 0; j < 6; ++j) acc[4 + j] += comp[sub][4 + j][k] * w5;
    }
    float D[3][3] = {
        { acc[0] + acc[4],  acc[1] + acc[5],  acc[2] + acc[6] },
        { -acc[1] + acc[5], acc[0] + acc[7],  acc[3] + acc[8] },
        { -acc[2] + acc[6], -acc[3] + acc[8], acc[0] + acc[9] } };

    if (n < N) {
        float* ob = out + (size_t)n * 9 * HD + h;
#pragma unroll
        for (int a = 0; a < 3; ++a) {
#pragma unroll
            for (int b = 0; b < 3; ++b) {
                float s = 0.f;
#pragma unroll
                for (int c = 0; c < 3; ++c) s += D[a][c] * D[c][b];
                ob[(a * 3 + b) * HD] = x[a * 3 + b] + D[a][b] + s;
            }
        }
    }
}

// ---------------- launch ------------------------------------------------------
extern "C" void kernel_launch(void* const* d_in, const int* in_sizes, int n_in,
                              void* d_out, int out_size, void* d_ws, size_t ws_size,
                              hipStream_t stream)
{
    const float* X           = (const float*)d_in[0];
    const float* charges     = (const float*)d_in[1];
    const float* edge_weight = (const float*)d_in[2];
    const float* edge_attr   = (const float*)d_in[3];
    const int*   edge_index  = (const int*)d_in[4];
    const float* Ws1 = (const float*)d_in[5];
    const float* bs1 = (const float*)d_in[6];
    const float* Ws2 = (const float*)d_in[7];
    const float* bs2 = (const float*)d_in[8];
    const float* Ws3 = (const float*)d_in[9];
    const float* bs3 = (const float*)d_in[10];
    const float* Wt0 = (const float*)d_in[11];
    const float* Wt1 = (const float*)d_in[12];
    const float* Wt2 = (const float*)d_in[13];
    const float* Wt3 = (const float*)d_in[14];
    const float* Wt4 = (const float*)d_in[15];
    const float* Wt5 = (const float*)d_in[16];

    int N = in_sizes[0] / (9 * HD);
    int E = in_sizes[2];

    _Float16* TnH  = (_Float16*)d_ws;                  // N*640 f16
    _Float16* MnH  = TnH + (size_t)N * 640;            // N*640 f16
    _Float16* bufH = MnH + (size_t)N * 640;            // E*192 f16 (CSR slots)
    int* cnt   = (int*)(bufH + (size_t)E * 192);       // N
    int* offs  = cnt + N;                              // N+1
    int* curs  = offs + N + 1;                         // N
    int* colP  = curs + N;                             // E
    size_t fofs = ((size_t)((char*)(colP + E) - (char*)d_ws) + 15) & ~(size_t)15;
    _Float16* W1f = (_Float16*)((char*)d_ws + fofs);   // 4096
    _Float16* W2f = W1f + 4096;                        // 8192
    _Float16* W3f = W2f + 8192;                        // 24576

    hipMemsetAsync(cnt, 0, (size_t)N * sizeof(int), stream);

    int nbPre = (N + 3) / 4;
    int nbE256 = (E + 255) / 256;
    pre_wconv_count<<<nbPre + 144 + nbE256, 256, 0, stream>>>(
        X, Wt0, Wt1, Wt2, TnH, N, nbPre,
        Ws1, Ws2, Ws3, W1f, W2f, W3f, edge_index, cnt, E);

    scan_kernel<<<1, 1024, 0, stream>>>(cnt, offs, curs, N);

    int nbE64 = (E + 63) / 64;
    mlp_mfma<<<nbE64, 256, 0, stream>>>(edge_attr, charges, edge_weight, edge_index,
                                        curs, colP, W1f, bs1, W2f, bs2, W3f, bs3, bufH, E);

    msg_kernel<<<N, 256, 0, stream>>>(bufH, colP, offs, TnH, MnH, N);

    node_post<<<(N + 3) / 4, 256, 0, stream>>>(X, TnH, MnH, Wt3, Wt4, Wt5, (float*)d_out, N);
}